// Round 2
// baseline (213.101 us; speedup 1.0000x reference)
//
#include <hip/hip_runtime.h>
#include <hip/hip_bf16.h>

// Problem: B=8192 rows, F=4096 features, K=64 factors.
// out[b] = 0.5 * ( ||x_b @ v||^2  -  (x_b^2) . w ),  w[f] = sum_k v[f][k]^2

#define F_DIM 4096
#define K_DIM 64
#define B_ROWS 8192

typedef __attribute__((ext_vector_type(8))) short short8;
typedef __attribute__((ext_vector_type(4))) float float4v;
typedef __attribute__((ext_vector_type(16))) float f32x16;

__device__ __forceinline__ short f2bs(float f) {
    __hip_bfloat16 h = __float2bfloat16(f);
    short s;
    __builtin_memcpy(&s, &h, 2);
    return s;
}

// Prep: vt[n][f] = bf16(v[f][n]); w[f] = sum_n v[f][n]^2
__global__ void prep_kernel(const float* __restrict__ v,
                            __hip_bfloat16* __restrict__ vt,
                            float* __restrict__ w) {
    const int wave = (blockIdx.x * blockDim.x + threadIdx.x) >> 6;
    const int lane = threadIdx.x & 63;
    if (wave >= F_DIM) return;
    const float val = v[wave * K_DIM + lane];
    float sq = val * val;
#pragma unroll
    for (int m = 32; m >= 1; m >>= 1) sq += __shfl_xor(sq, m, 64);
    if (lane == 0) w[wave] = sq;
    vt[(size_t)lane * F_DIM + wave] = __float2bfloat16(val);
}

// Main: block = 32 rows, 1024 threads = 16 waves, 16-way f-split (256 f each).
// 32x32x16 MFMA: 2 MFMA + 2 vt-loads per 2KB of x (vs 4+4 with 16x16).
__launch_bounds__(1024, 4)
__global__ void fm_main_kernel(const float* __restrict__ x,
                               const __hip_bfloat16* __restrict__ vt,
                               const float* __restrict__ w,
                               float* __restrict__ out) {
    __shared__ float yred[8][32][64];   // 64 KB two-phase reduction
    __shared__ float s1s[32];
    __shared__ float s2s[32];

    const int tid  = threadIdx.x;
    const int lane = tid & 63;
    const int wid  = tid >> 6;           // 0..15
    const int lrow = lane & 31;          // MFMA A row / B col (within group)
    const int lk8  = (lane >> 5) * 8;    // MFMA k offset (8 contiguous)
    const int row0 = blockIdx.x * 32;

    if (tid < 32) s2s[tid] = 0.0f;
    __syncthreads();

    const float* xrow = x + (size_t)(row0 + lrow) * F_DIM;
    const int fbase = wid * (F_DIM / 16);   // 256 f per wave

    f32x16 acc0{};   // cols 0..31
    f32x16 acc1{};   // cols 32..63
    float s2p = 0.0f;

#pragma unroll 2
    for (int ks = 0; ks < 16; ++ks) {    // 16 k-steps of 16 f
        const int fo = fbase + ks * 16 + lk8;
        const float4v xa = *(const float4v*)(xrow + fo);
        const float4v xb = *(const float4v*)(xrow + fo + 4);
        const float4v wa = *(const float4v*)(w + fo);
        const float4v wb = *(const float4v*)(w + fo + 4);

        s2p += xa.x*xa.x*wa.x + xa.y*xa.y*wa.y + xa.z*xa.z*wa.z + xa.w*xa.w*wa.w
             + xb.x*xb.x*wb.x + xb.y*xb.y*wb.y + xb.z*xb.z*wb.z + xb.w*xb.w*wb.w;

        short8 af;
        af[0]=f2bs(xa.x); af[1]=f2bs(xa.y); af[2]=f2bs(xa.z); af[3]=f2bs(xa.w);
        af[4]=f2bs(xb.x); af[5]=f2bs(xb.y); af[6]=f2bs(xb.z); af[7]=f2bs(xb.w);

        const __hip_bfloat16* bb = vt + fo;
        const short8 b0 = *(const short8*)(bb + (size_t)lrow * F_DIM);
        const short8 b1 = *(const short8*)(bb + (size_t)(32 + lrow) * F_DIM);

        acc0 = __builtin_amdgcn_mfma_f32_32x32x16_bf16(af, b0, acc0, 0, 0, 0);
        acc1 = __builtin_amdgcn_mfma_f32_32x32x16_bf16(af, b1, acc1, 0, 0, 0);
    }

    // s2: lanes l and l+32 cover the two k-halves of row l
    s2p += __shfl_xor(s2p, 32, 64);
    if (lane < 32) atomicAdd(&s2s[lrow], s2p);

    // y partials. D layout (32x32): col = lane&31, row = (r&3) + 8*(r>>2) + 4*(lane>>5)
    const int rbase = 4 * (lane >> 5);
    if (wid < 8) {
#pragma unroll
        for (int r = 0; r < 16; ++r) {
            const int row = (r & 3) + 8 * (r >> 2) + rbase;
            yred[wid][row][lrow]      = acc0[r];
            yred[wid][row][32 + lrow] = acc1[r];
        }
    }
    __syncthreads();
    if (wid >= 8) {
#pragma unroll
        for (int r = 0; r < 16; ++r) {
            const int row = (r & 3) + 8 * (r >> 2) + rbase;
            yred[wid - 8][row][lrow]      += acc0[r];
            yred[wid - 8][row][32 + lrow] += acc1[r];
        }
    }
    __syncthreads();

    // s1: wave wid reduces rows {2*wid, 2*wid+1}; lane = column
#pragma unroll
    for (int h = 0; h < 2; ++h) {
        const int row = 2 * wid + h;
        float y = 0.0f;
#pragma unroll
        for (int s = 0; s < 8; ++s) y += yred[s][row][lane];
        float yy = y * y;
#pragma unroll
        for (int m = 32; m >= 1; m >>= 1) yy += __shfl_xor(yy, m, 64);
        if (lane == 0) s1s[row] = yy;
    }
    __syncthreads();

    if (tid < 32) out[row0 + tid] = 0.5f * (s1s[tid] - s2s[tid]);
}

extern "C" void kernel_launch(void* const* d_in, const int* in_sizes, int n_in,
                              void* d_out, int out_size, void* d_ws, size_t ws_size,
                              hipStream_t stream) {
    const float* x = (const float*)d_in[0];   // [8192, 4096] fp32
    const float* v = (const float*)d_in[1];   // [4096, 64]   fp32
    float* out = (float*)d_out;               // [8192]       fp32

    __hip_bfloat16* vt = (__hip_bfloat16*)d_ws;                    // 512 KB
    float* w = (float*)((char*)d_ws + (size_t)K_DIM * F_DIM * 2);  // 16 KB

    prep_kernel<<<F_DIM / 4, 256, 0, stream>>>(v, vt, w);
    fm_main_kernel<<<B_ROWS / 32, 1024, 0, stream>>>(x, vt, w, out);
}

// Round 3
// 203.292 us; speedup vs baseline: 1.0483x; 1.0483x over previous
//
#include <hip/hip_runtime.h>
#include <hip/hip_bf16.h>

// Problem: B=8192 rows, F=4096 features, K=64 factors.
// out[b] = 0.5 * ( ||x_b @ v||^2  -  (x_b^2) . w ),  w[f] = sum_k v[f][k]^2
//
// vtf fragment-ordered layout: vtf[fc][c][lane][j] = v[fc*16 + 8*(lane>>5) + j][c*32 + (lane&31)]
// -> main kernel's B-fragment load is 64 lanes x consecutive 16B = dense 1KB L2 read.

#define F_DIM 4096
#define K_DIM 64
#define B_ROWS 8192

typedef __attribute__((ext_vector_type(8))) short short8;
typedef __attribute__((ext_vector_type(4))) float float4v;
typedef __attribute__((ext_vector_type(16))) float f32x16;

__device__ __forceinline__ short f2bs(float f) {
    __hip_bfloat16 h = __float2bfloat16(f);
    short s;
    __builtin_memcpy(&s, &h, 2);
    return s;
}

// Prep: one wave per 16-row chunk of v (16 f-rows x 64 k-cols = 4KB, coalesced).
// Emits w[f] and the fragment-ordered vtf (coalesced 1KB writes via LDS transpose).
__global__ void prep_kernel(const float* __restrict__ v,
                            short* __restrict__ vtf,
                            float* __restrict__ w) {
    __shared__ short lds_t[4][64][16];   // per wave: [k][r] bf16

    const int wid  = threadIdx.x >> 6;
    const int lane = threadIdx.x & 63;
    const int fc   = blockIdx.x * 4 + wid;   // 0..255
    const int r    = lane >> 2;              // row within chunk 0..15
    const int k0   = (lane & 3) * 16;        // 0..48

    const float* src = v + (size_t)(fc * 16 + r) * K_DIM + k0;
    float vals[16];
#pragma unroll
    for (int i = 0; i < 16; i += 4) {
        float4v t = *(const float4v*)(src + i);
        vals[i] = t.x; vals[i+1] = t.y; vals[i+2] = t.z; vals[i+3] = t.w;
    }

    float sq = 0.0f;
#pragma unroll
    for (int i = 0; i < 16; ++i) sq += vals[i] * vals[i];
    sq += __shfl_xor(sq, 1, 64);
    sq += __shfl_xor(sq, 2, 64);
    if ((lane & 3) == 0) w[fc * 16 + r] = sq;

#pragma unroll
    for (int kk = 0; kk < 16; ++kk) lds_t[wid][k0 + kk][r] = f2bs(vals[kk]);
    __syncthreads();

#pragma unroll
    for (int c = 0; c < 2; ++c) {
        const short8 frag = *(const short8*)&lds_t[wid][c * 32 + (lane & 31)][8 * (lane >> 5)];
        *(short8*)(vtf + ((size_t)fc * 2 + c) * 512 + lane * 8) = frag;
    }
}

// Main: block = 32 rows, 1024 threads = 16 waves, 16-way f-split (256 f each).
__launch_bounds__(1024, 4)
__global__ void fm_main_kernel(const float* __restrict__ x,
                               const short* __restrict__ vtf,
                               const float* __restrict__ w,
                               float* __restrict__ out) {
    __shared__ float yred[8][32][64];   // 64 KB two-phase reduction
    __shared__ float s1s[32];
    __shared__ float s2s[32];

    const int tid  = threadIdx.x;
    const int lane = tid & 63;
    const int wid  = tid >> 6;           // 0..15
    const int lrow = lane & 31;          // MFMA A row
    const int lk8  = (lane >> 5) * 8;    // MFMA k offset (8 contiguous)
    const int row0 = blockIdx.x * 32;

    if (tid < 32) s2s[tid] = 0.0f;
    __syncthreads();

    const float* xrow = x + (size_t)(row0 + lrow) * F_DIM;
    const int fbase = wid * (F_DIM / 16);   // 256 f per wave
    const int fcbase = fbase >> 4;          // f-chunk base for vtf

    f32x16 acc0{};   // cols 0..31
    f32x16 acc1{};   // cols 32..63
    float s2p = 0.0f;

#pragma unroll 2
    for (int ks = 0; ks < 16; ++ks) {    // 16 k-steps of 16 f
        const int fo = fbase + ks * 16 + lk8;
        const float4v xa = *(const float4v*)(xrow + fo);
        const float4v xb = *(const float4v*)(xrow + fo + 4);
        const float4v wa = *(const float4v*)(w + fo);
        const float4v wb = *(const float4v*)(w + fo + 4);

        s2p += xa.x*xa.x*wa.x + xa.y*xa.y*wa.y + xa.z*xa.z*wa.z + xa.w*xa.w*wa.w
             + xb.x*xb.x*wb.x + xb.y*xb.y*wb.y + xb.z*xb.z*wb.z + xb.w*xb.w*wb.w;

        short8 af;
        af[0]=f2bs(xa.x); af[1]=f2bs(xa.y); af[2]=f2bs(xa.z); af[3]=f2bs(xa.w);
        af[4]=f2bs(xb.x); af[5]=f2bs(xb.y); af[6]=f2bs(xb.z); af[7]=f2bs(xb.w);

        // Fragment-ordered B loads: dense 1KB per wave, L2-resident.
        const size_t fc = (size_t)(fcbase + ks) * 2;
        const short8 b0 = *(const short8*)(vtf + (fc + 0) * 512 + lane * 8);
        const short8 b1 = *(const short8*)(vtf + (fc + 1) * 512 + lane * 8);

        acc0 = __builtin_amdgcn_mfma_f32_32x32x16_bf16(af, b0, acc0, 0, 0, 0);
        acc1 = __builtin_amdgcn_mfma_f32_32x32x16_bf16(af, b1, acc1, 0, 0, 0);
    }

    // s2: lanes l and l+32 cover the two k-halves of row l
    s2p += __shfl_xor(s2p, 32, 64);
    if (lane < 32) atomicAdd(&s2s[lrow], s2p);

    // y partials. D layout (32x32): col = lane&31, row = (r&3) + 8*(r>>2) + 4*(lane>>5)
    const int rbase = 4 * (lane >> 5);
    if (wid < 8) {
#pragma unroll
        for (int r = 0; r < 16; ++r) {
            const int row = (r & 3) + 8 * (r >> 2) + rbase;
            yred[wid][row][lrow]      = acc0[r];
            yred[wid][row][32 + lrow] = acc1[r];
        }
    }
    __syncthreads();
    if (wid >= 8) {
#pragma unroll
        for (int r = 0; r < 16; ++r) {
            const int row = (r & 3) + 8 * (r >> 2) + rbase;
            yred[wid - 8][row][lrow]      += acc0[r];
            yred[wid - 8][row][32 + lrow] += acc1[r];
        }
    }
    __syncthreads();

    // s1: wave wid reduces rows {2*wid, 2*wid+1}; lane = column
#pragma unroll
    for (int h = 0; h < 2; ++h) {
        const int row = 2 * wid + h;
        float y = 0.0f;
#pragma unroll
        for (int s = 0; s < 8; ++s) y += yred[s][row][lane];
        float yy = y * y;
#pragma unroll
        for (int m = 32; m >= 1; m >>= 1) yy += __shfl_xor(yy, m, 64);
        if (lane == 0) s1s[row] = yy;
    }
    __syncthreads();

    if (tid < 32) out[row0 + tid] = 0.5f * (s1s[tid] - s2s[tid]);
}

extern "C" void kernel_launch(void* const* d_in, const int* in_sizes, int n_in,
                              void* d_out, int out_size, void* d_ws, size_t ws_size,
                              hipStream_t stream) {
    const float* x = (const float*)d_in[0];   // [8192, 4096] fp32
    const float* v = (const float*)d_in[1];   // [4096, 64]   fp32
    float* out = (float*)d_out;               // [8192]       fp32

    short* vtf = (short*)d_ws;                                     // 512 KB
    float* w = (float*)((char*)d_ws + (size_t)K_DIM * F_DIM * 2);  // 16 KB

    prep_kernel<<<F_DIM / 16 / 4, 256, 0, stream>>>(v, vtf, w);
    fm_main_kernel<<<B_ROWS / 32, 1024, 0, stream>>>(x, vtf, w, out);
}

// Round 4
// 199.872 us; speedup vs baseline: 1.0662x; 1.0171x over previous
//
#include <hip/hip_runtime.h>
#include <hip/hip_bf16.h>
#include <stdint.h>

// Problem: B=8192 rows, F=4096 features, K=64 factors.
// out[b] = 0.5 * ( ||x_b @ v||^2  -  (x_b^2) . w ),  w[f] = sum_k v[f][k]^2
//
// Main kernel: per-wave-private LDS ring staged by global_load_lds (width 16),
// depth-3 prefetch, counted vmcnt (never 0 until drain), NO barriers in loop.

#define F_DIM 4096
#define K_DIM 64
#define B_ROWS 8192

typedef __attribute__((ext_vector_type(8))) short short8;
typedef __attribute__((ext_vector_type(4))) float float4v;
typedef __attribute__((ext_vector_type(16))) float f32x16;

typedef __attribute__((address_space(3))) uint32_t lds_u32;
typedef const __attribute__((address_space(1))) uint32_t glb_u32;

__device__ __forceinline__ void load_lds16(const void* g, void* l) {
    // LDS dest: wave-uniform base; HW writes base + lane*16. Global src per-lane.
    __builtin_amdgcn_global_load_lds((glb_u32*)(uintptr_t)g,
                                     (lds_u32*)(uint32_t)(uintptr_t)l,
                                     16, 0, 0);
}

__device__ __forceinline__ short f2bs(float f) {
    __hip_bfloat16 h = __float2bfloat16(f);
    short s;
    __builtin_memcpy(&s, &h, 2);
    return s;
}

// Prep (unchanged from passing round-3): fragment-ordered vtf + w.
// vtf[fc][c][lane][j] = v[fc*16 + 8*(lane>>5)+j][c*32 + (lane&31)]
__global__ void prep_kernel(const float* __restrict__ v,
                            short* __restrict__ vtf,
                            float* __restrict__ w) {
    __shared__ short lds_t[4][64][16];

    const int wid  = threadIdx.x >> 6;
    const int lane = threadIdx.x & 63;
    const int fc   = blockIdx.x * 4 + wid;
    const int r    = lane >> 2;
    const int k0   = (lane & 3) * 16;

    const float* src = v + (size_t)(fc * 16 + r) * K_DIM + k0;
    float vals[16];
#pragma unroll
    for (int i = 0; i < 16; i += 4) {
        float4v t = *(const float4v*)(src + i);
        vals[i] = t.x; vals[i+1] = t.y; vals[i+2] = t.z; vals[i+3] = t.w;
    }

    float sq = 0.0f;
#pragma unroll
    for (int i = 0; i < 16; ++i) sq += vals[i] * vals[i];
    sq += __shfl_xor(sq, 1, 64);
    sq += __shfl_xor(sq, 2, 64);
    if ((lane & 3) == 0) w[fc * 16 + r] = sq;

#pragma unroll
    for (int kk = 0; kk < 16; ++kk) lds_t[wid][k0 + kk][r] = f2bs(vals[kk]);
    __syncthreads();

#pragma unroll
    for (int c = 0; c < 2; ++c) {
        const short8 frag = *(const short8*)&lds_t[wid][c * 32 + (lane & 31)][8 * (lane >> 5)];
        *(short8*)(vtf + ((size_t)fc * 2 + c) * 512 + lane * 8) = frag;
    }
}

// Main: 256 blocks x 512 thr (8 waves). 32 rows/block, 8-way f-split (512 f/wave,
// 32 k-steps of 16). Ring entry (4KB): [x 2KB][vtf 2KB]; 4 entries/wave.
__launch_bounds__(512, 2)
__global__ void fm_main_kernel(const float* __restrict__ x,
                               const short* __restrict__ vtf,
                               const float* __restrict__ w,
                               float* __restrict__ out) {
    __shared__ __align__(16) char ring[8][4][4096];  // 128 KB (reused as yred)
    __shared__ __align__(16) float wlds[8][512];     // 16 KB
    __shared__ float s2red[8][32];                   // 1 KB

    const int tid  = threadIdx.x;
    const int lane = tid & 63;
    const int wid  = tid >> 6;        // 0..7
    const int lrow = lane & 31;       // MFMA A row
    const int hi   = lane >> 5;       // k-half select
    const int row0 = blockIdx.x * 32;
    const int fbase = wid * 512;
    const int fcb2  = wid * 32;       // 16-f chunk base

    // Per-lane global source for x staging (16B per lane):
    //   instr0 lane l -> row (l&31), floats (l>>5)*4 + 0..3 ; instr1 = +8 floats
    const float* gx_base = x + (size_t)(row0 + lrow) * F_DIM + fbase + hi * 4;

#define STAGE(t) do {                                                     \
        char* eb_ = &ring[wid][(t) & 3][0];                               \
        const float* gx_ = gx_base + (t) * 16;                            \
        load_lds16(gx_,     eb_);                                         \
        load_lds16(gx_ + 8, eb_ + 1024);                                  \
        const short* gv_ = vtf + ((size_t)(fcb2 + (t))) * 1024 + lane * 8;\
        load_lds16(gv_,       eb_ + 2048);                                \
        load_lds16(gv_ + 512, eb_ + 3072);                                \
    } while (0)

    // w slice -> LDS (2 loads, issued first so first vmcnt drains them too)
    load_lds16(w + fbase + lane * 4,       &wlds[wid][0]);
    load_lds16(w + fbase + 256 + lane * 4, &wlds[wid][256]);

    STAGE(0); STAGE(1); STAGE(2);

    f32x16 acc0{};   // cols 0..31
    f32x16 acc1{};   // cols 32..63
    float s2p = 0.0f;

    const int xoff = hi * 1024 + lrow * 16;   // bytes within entry
    const int woff = hi * 32;                  // bytes within w row-chunk

#pragma unroll
    for (int t = 0; t < 32; ++t) {
        if (t + 3 < 32) STAGE(t + 3);
        // FIFO: outstanding = w(first iter) + stages t..t+3; leave 3 stages in flight.
        if (t < 29)       asm volatile("s_waitcnt vmcnt(12)" ::: "memory");
        else if (t == 29) asm volatile("s_waitcnt vmcnt(8)"  ::: "memory");
        else if (t == 30) asm volatile("s_waitcnt vmcnt(4)"  ::: "memory");
        else              asm volatile("s_waitcnt vmcnt(0)"  ::: "memory");
        __builtin_amdgcn_sched_barrier(0);

        const char* eb = &ring[wid][t & 3][0];
        const float4v xa = *(const float4v*)(eb + xoff);
        const float4v xb = *(const float4v*)(eb + xoff + 512);
        const short8  b0 = *(const short8*)(eb + 2048 + lane * 16);
        const short8  b1 = *(const short8*)(eb + 3072 + lane * 16);
        const char* wp = (const char*)&wlds[wid][0] + t * 64 + woff;
        const float4v wa = *(const float4v*)(wp);
        const float4v wb = *(const float4v*)(wp + 16);

        s2p += xa.x*xa.x*wa.x + xa.y*xa.y*wa.y + xa.z*xa.z*wa.z + xa.w*xa.w*wa.w
             + xb.x*xb.x*wb.x + xb.y*xb.y*wb.y + xb.z*xb.z*wb.z + xb.w*xb.w*wb.w;

        short8 af;
        af[0]=f2bs(xa.x); af[1]=f2bs(xa.y); af[2]=f2bs(xa.z); af[3]=f2bs(xa.w);
        af[4]=f2bs(xb.x); af[5]=f2bs(xb.y); af[6]=f2bs(xb.z); af[7]=f2bs(xb.w);

        acc0 = __builtin_amdgcn_mfma_f32_32x32x16_bf16(af, b0, acc0, 0, 0, 0);
        acc1 = __builtin_amdgcn_mfma_f32_32x32x16_bf16(af, b1, acc1, 0, 0, 0);
    }
#undef STAGE

    // s2 partials: lanes l / l+32 hold disjoint k-halves of row l
    s2p += __shfl_xor(s2p, 32, 64);
    if (lane < 32) s2red[wid][lrow] = s2p;

    __syncthreads();   // all waves done with ring -> reuse as yred

    float (*yred)[32][64] = (float (*)[32][64])&ring[0][0][0];  // 64 KB
    const int rbase = 4 * hi;
#pragma unroll
    for (int r = 0; r < 16; ++r) {
        const int row = (r & 3) + 8 * (r >> 2) + rbase;
        yred[wid][row][lrow]      = acc0[r];
        yred[wid][row][32 + lrow] = acc1[r];
    }
    __syncthreads();

    // each wave reduces 4 rows; lane = column
#pragma unroll
    for (int h = 0; h < 4; ++h) {
        const int row = wid * 4 + h;
        float y = 0.0f;
#pragma unroll
        for (int s = 0; s < 8; ++s) y += yred[s][row][lane];
        float yy = y * y;
#pragma unroll
        for (int m = 32; m >= 1; m >>= 1) yy += __shfl_xor(yy, m, 64);
        if (lane == 0) {
            float s2 = 0.0f;
#pragma unroll
            for (int s = 0; s < 8; ++s) s2 += s2red[s][row];
            out[row0 + row] = 0.5f * (yy - s2);
        }
    }
}

extern "C" void kernel_launch(void* const* d_in, const int* in_sizes, int n_in,
                              void* d_out, int out_size, void* d_ws, size_t ws_size,
                              hipStream_t stream) {
    const float* x = (const float*)d_in[0];   // [8192, 4096] fp32
    const float* v = (const float*)d_in[1];   // [4096, 64]   fp32
    float* out = (float*)d_out;               // [8192]       fp32

    short* vtf = (short*)d_ws;                                     // 512 KB
    float* w = (float*)((char*)d_ws + (size_t)K_DIM * F_DIM * 2);  // 16 KB

    prep_kernel<<<F_DIM / 16 / 4, 256, 0, stream>>>(v, vtf, w);
    fm_main_kernel<<<B_ROWS / 32, 512, 0, stream>>>(x, vtf, w, out);
}

// Round 6
// 197.731 us; speedup vs baseline: 1.0777x; 1.0108x over previous
//
#include <hip/hip_runtime.h>
#include <hip/hip_bf16.h>
#include <stdint.h>

// Problem: B=8192 rows, F=4096 features, K=64 factors.
// out[b] = 0.5 * ( ||x_b @ v||^2  -  (x_b^2) . w ),  w[f] = sum_k v[f][k]^2
//
// Round-5 structure: simplest pipeline (direct global->reg loads, no staging LDS),
// with INTERLEAVED f-chunks: wave w, step t handles chunk c = t*8 + w, so the
// block sweeps each x-row contiguously (512B strides) -> DRAM-sequential streams.

#define F_DIM 4096
#define K_DIM 64
#define B_ROWS 8192

typedef __attribute__((ext_vector_type(8))) short short8;
typedef __attribute__((ext_vector_type(4))) float float4v;
typedef __attribute__((ext_vector_type(16))) float f32x16;

__device__ __forceinline__ short f2bs(float f) {
    __hip_bfloat16 h = __float2bfloat16(f);
    short s;
    __builtin_memcpy(&s, &h, 2);
    return s;
}

// Prep (unchanged, passing since round 3): fragment-ordered vtf + w.
// vtf[fc][c2][lane][j] = v[fc*16 + 8*(lane>>5)+j][c2*32 + (lane&31)]
__global__ void prep_kernel(const float* __restrict__ v,
                            short* __restrict__ vtf,
                            float* __restrict__ w) {
    __shared__ short lds_t[4][64][16];

    const int wid  = threadIdx.x >> 6;
    const int lane = threadIdx.x & 63;
    const int fc   = blockIdx.x * 4 + wid;
    const int r    = lane >> 2;
    const int k0   = (lane & 3) * 16;

    const float* src = v + (size_t)(fc * 16 + r) * K_DIM + k0;
    float vals[16];
#pragma unroll
    for (int i = 0; i < 16; i += 4) {
        float4v t = *(const float4v*)(src + i);
        vals[i] = t.x; vals[i+1] = t.y; vals[i+2] = t.z; vals[i+3] = t.w;
    }

    float sq = 0.0f;
#pragma unroll
    for (int i = 0; i < 16; ++i) sq += vals[i] * vals[i];
    sq += __shfl_xor(sq, 1, 64);
    sq += __shfl_xor(sq, 2, 64);
    if ((lane & 3) == 0) w[fc * 16 + r] = sq;

#pragma unroll
    for (int kk = 0; kk < 16; ++kk) lds_t[wid][k0 + kk][r] = f2bs(vals[kk]);
    __syncthreads();

#pragma unroll
    for (int c = 0; c < 2; ++c) {
        const short8 frag = *(const short8*)&lds_t[wid][c * 32 + (lane & 31)][8 * (lane >> 5)];
        *(short8*)(vtf + ((size_t)fc * 2 + c) * 512 + lane * 8) = frag;
    }
}

// Main: 256 blocks x 512 thr (8 waves), 32 rows/block, interleaved f-chunks.
// Step t, wave w -> f-chunk c = t*8 + w (f0 = c*16). 32 steps cover all 4096 f.
__launch_bounds__(512, 4)
__global__ void fm_main_kernel(const float* __restrict__ x,
                               const short* __restrict__ vtf,
                               const float* __restrict__ w,
                               float* __restrict__ out) {
    __shared__ float yred[8][32][64];   // 64 KB
    __shared__ float s2red[8][32];      // 1 KB

    const int tid  = threadIdx.x;
    const int lane = tid & 63;
    const int wid  = tid >> 6;        // 0..7
    const int lrow = lane & 31;       // MFMA A row / B col
    const int hi   = lane >> 5;       // k-half select
    const int row0 = blockIdx.x * 32;

    // Per-lane bases; step t adds t*128 floats (x,w) / t*8192 shorts (vtf).
    const float* xrow  = x + (size_t)(row0 + lrow) * F_DIM + wid * 16 + hi * 8;
    const float* wbase = w + wid * 16 + hi * 8;
    const short* vbase = vtf + (size_t)wid * 1024 + (size_t)lane * 8;

    f32x16 acc0{};   // cols 0..31
    f32x16 acc1{};   // cols 32..63
    float s2p = 0.0f;

#pragma unroll 2
    for (int t = 0; t < 32; ++t) {
        const float4v xa = *(const float4v*)(xrow + t * 128);
        const float4v xb = *(const float4v*)(xrow + t * 128 + 4);
        const float4v wa = *(const float4v*)(wbase + t * 128);
        const float4v wb = *(const float4v*)(wbase + t * 128 + 4);
        const short8  b0 = *(const short8*)(vbase + (size_t)t * 8192);
        const short8  b1 = *(const short8*)(vbase + (size_t)t * 8192 + 512);

        s2p += xa.x*xa.x*wa.x + xa.y*xa.y*wa.y + xa.z*xa.z*wa.z + xa.w*xa.w*wa.w
             + xb.x*xb.x*wb.x + xb.y*xb.y*wb.y + xb.z*xb.z*wb.z + xb.w*xb.w*wb.w;

        short8 af;
        af[0]=f2bs(xa.x); af[1]=f2bs(xa.y); af[2]=f2bs(xa.z); af[3]=f2bs(xa.w);
        af[4]=f2bs(xb.x); af[5]=f2bs(xb.y); af[6]=f2bs(xb.z); af[7]=f2bs(xb.w);

        acc0 = __builtin_amdgcn_mfma_f32_32x32x16_bf16(af, b0, acc0, 0, 0, 0);
        acc1 = __builtin_amdgcn_mfma_f32_32x32x16_bf16(af, b1, acc1, 0, 0, 0);
    }

    // s2: lanes l and l+32 hold the two k-halves of row l
    s2p += __shfl_xor(s2p, 32, 64);
    if (lane < 32) s2red[wid][lrow] = s2p;

    // y partials. D layout (32x32): col = lane&31, row = (r&3) + 8*(r>>2) + 4*hi
    const int rbase = 4 * hi;
#pragma unroll
    for (int r = 0; r < 16; ++r) {
        const int row = (r & 3) + 8 * (r >> 2) + rbase;
        yred[wid][row][lrow]      = acc0[r];
        yred[wid][row][32 + lrow] = acc1[r];
    }
    __syncthreads();

    // each wave reduces 4 rows; lane = column
#pragma unroll
    for (int h = 0; h < 4; ++h) {
        const int row = wid * 4 + h;
        float y = 0.0f;
#pragma unroll
        for (int s = 0; s < 8; ++s) y += yred[s][row][lane];
        float yy = y * y;
#pragma unroll
        for (int m = 32; m >= 1; m >>= 1) yy += __shfl_xor(yy, m, 64);
        if (lane == 0) {
            float s2 = 0.0f;
#pragma unroll
            for (int s = 0; s < 8; ++s) s2 += s2red[s][row];
            out[row0 + row] = 0.5f * (yy - s2);
        }
    }
}

extern "C" void kernel_launch(void* const* d_in, const int* in_sizes, int n_in,
                              void* d_out, int out_size, void* d_ws, size_t ws_size,
                              hipStream_t stream) {
    const float* x = (const float*)d_in[0];   // [8192, 4096] fp32
    const float* v = (const float*)d_in[1];   // [4096, 64]   fp32
    float* out = (float*)d_out;               // [8192]       fp32

    short* vtf = (short*)d_ws;                                     // 512 KB
    float* w = (float*)((char*)d_ws + (size_t)K_DIM * F_DIM * 2);  // 16 KB

    prep_kernel<<<F_DIM / 16 / 4, 256, 0, stream>>>(v, vtf, w);
    fm_main_kernel<<<B_ROWS / 32, 512, 0, stream>>>(x, vtf, w, out);
}